// Round 7
// baseline (641.747 us; speedup 1.0000x reference)
//
#include <hip/hip_runtime.h>
#include <stdint.h>

#define BS   8
#define CH   256    // C
#define LSEQ 4096   // H*W
#define DIN  256    // INNER
#define NT2  128    // number of KV tiles (32 rows each)
#define KT2  32     // kv rows per tile

typedef __bf16 bf16x8 __attribute__((ext_vector_type(8)));
typedef __bf16 bf16x4 __attribute__((ext_vector_type(4)));
typedef float  f32x4  __attribute__((ext_vector_type(4)));

// async global->LDS, 16B per lane; LDS dest = wave-uniform base + lane*16
__device__ __forceinline__ void gload_lds16(const void* g, void* l) {
    __builtin_amdgcn_global_load_lds(
        (const __attribute__((address_space(1))) uint32_t*)g,
        (__attribute__((address_space(3))) uint32_t*)l, 16, 0, 0);
}

// ---------------------------------------------------------------------------
// Kernel 1: QKV projection. Y[l][i] = sum_c X[c][l]*W[i][c] + b[i].
// which==0 -> Q linear [l][i] bf16.
// which==1 -> K into swizzled tile image: tile(b,t2) 32KB, K half 16KB:
//             byte = row*512 + ((2i) ^ ((row&7)<<4)), row = l&31.
// which==2 -> V half at +16384: d-pair rows of 128B:
//             byte = 16384 + (d>>1)*128 + (((d&1)*64 + 2*(l&31)) ^ (((d>>1)&7)<<4)).
// Tile stride 32KB; base = (b*128 + t2) << 15.
// ---------------------------------------------------------------------------
__global__ __launch_bounds__(256) void qkv_proj_kernel(
    const float* __restrict__ x,
    const float* __restrict__ Wq, const float* __restrict__ bq,
    const float* __restrict__ Wk, const float* __restrict__ bk,
    const float* __restrict__ Wv, const float* __restrict__ bv,
    __bf16* __restrict__ Q, uint8_t* __restrict__ KV)
{
    const int b     = blockIdx.z;
    const int which = blockIdx.y;
    const int l0    = blockIdx.x * 64;

    const float* W    = (which == 0) ? Wq : (which == 1) ? Wk : Wv;
    const float* bias = (which == 0) ? bq : (which == 1) ? bk : bv;
    const float* X    = x + (size_t)b * CH * LSEQ;

    __shared__ __align__(16) __bf16 sXt[64][40];   // [l][c]
    __shared__ __align__(16) __bf16 sW[256][40];   // [i][c]

    const int tid  = threadIdx.x;
    const int wv   = tid >> 6;
    const int lane = tid & 63;
    const int g    = lane >> 4;
    const int n16  = lane & 15;

    f32x4 acc[4][4];
    #pragma unroll
    for (int i = 0; i < 4; ++i)
        #pragma unroll
        for (int j = 0; j < 4; ++j)
            acc[i][j] = f32x4{0.f, 0.f, 0.f, 0.f};

    for (int kk = 0; kk < 8; ++kk) {
        const int c0 = kk * 32;
        __syncthreads();
        #pragma unroll
        for (int p = 0; p < 8; ++p) {
            const int i  = p * 32 + (tid >> 3);
            const int c4 = (tid & 7) * 4;
            const float4 v = *(const float4*)(W + (size_t)i * CH + c0 + c4);
            bf16x4 pk = { (__bf16)v.x, (__bf16)v.y, (__bf16)v.z, (__bf16)v.w };
            *(bf16x4*)&sW[i][c4] = pk;
        }
        #pragma unroll
        for (int p = 0; p < 2; ++p) {
            const int c  = p * 16 + (tid >> 4);
            const int l4 = (tid & 15) * 4;
            const float4 v = *(const float4*)(X + (size_t)(c0 + c) * LSEQ + l0 + l4);
            sXt[l4 + 0][c] = (__bf16)v.x;
            sXt[l4 + 1][c] = (__bf16)v.y;
            sXt[l4 + 2][c] = (__bf16)v.z;
            sXt[l4 + 3][c] = (__bf16)v.w;
        }
        __syncthreads();

        bf16x8 af[4], bfr[4];
        #pragma unroll
        for (int mr = 0; mr < 4; ++mr)
            af[mr] = *(const bf16x8*)&sXt[mr * 16 + n16][g * 8];
        #pragma unroll
        for (int nc = 0; nc < 4; ++nc)
            bfr[nc] = *(const bf16x8*)&sW[wv * 64 + nc * 16 + n16][g * 8];
        #pragma unroll
        for (int mr = 0; mr < 4; ++mr)
            #pragma unroll
            for (int nc = 0; nc < 4; ++nc)
                acc[mr][nc] = __builtin_amdgcn_mfma_f32_16x16x32_bf16(
                    af[mr], bfr[nc], acc[mr][nc], 0, 0, 0);
    }

    // D fragment: row l = mr*16 + g*4 + r, col i = nc*16 + n16 (+wv*64)
    if (which == 0) {
        __bf16* out = Q + (size_t)b * LSEQ * DIN;
        #pragma unroll
        for (int nc = 0; nc < 4; ++nc) {
            const int icol = wv * 64 + nc * 16 + n16;
            const float bb = bias[icol];
            #pragma unroll
            for (int mr = 0; mr < 4; ++mr) {
                const int lrow = l0 + mr * 16 + g * 4;
                #pragma unroll
                for (int r = 0; r < 4; ++r)
                    out[(size_t)(lrow + r) * DIN + icol] = (__bf16)(acc[mr][nc][r] + bb);
            }
        }
    } else if (which == 1) {
        #pragma unroll
        for (int nc = 0; nc < 4; ++nc) {
            const int icol = wv * 64 + nc * 16 + n16;
            const float bb = bias[icol];
            #pragma unroll
            for (int mr = 0; mr < 4; ++mr) {
                #pragma unroll
                for (int r = 0; r < 4; ++r) {
                    const int lrow = l0 + mr * 16 + g * 4 + r;
                    const int t2 = lrow >> 5, row = lrow & 31;
                    const size_t off = ((size_t)(b * NT2 + t2) << 15)
                                     + (size_t)row * 512
                                     + ((icol * 2) ^ ((row & 7) << 4));
                    *(__bf16*)(KV + off) = (__bf16)(acc[mr][nc][r] + bb);
                }
            }
        }
    } else {
        #pragma unroll
        for (int nc = 0; nc < 4; ++nc) {
            const int d  = wv * 64 + nc * 16 + n16;
            const float bb = bias[d];
            #pragma unroll
            for (int mr = 0; mr < 4; ++mr) {
                const int lrow = l0 + mr * 16 + g * 4;   // 4 consecutive l (8B run)
                const int t2 = lrow >> 5, c = lrow & 31;
                bf16x4 pk;
                #pragma unroll
                for (int r = 0; r < 4; ++r)
                    pk[r] = (__bf16)(acc[mr][nc][r] + bb);
                const size_t off = ((size_t)(b * NT2 + t2) << 15) + 16384
                                 + (size_t)(d >> 1) * 128
                                 + ((((d & 1) * 64) + 2 * c) ^ (((d >> 1) & 7) << 4));
                *(bf16x4*)(KV + off) = pk;
            }
        }
    }
}

// ---------------------------------------------------------------------------
// Kernel 2: flash attention v5 — arithmetic-intensity doubled.
// 256 thr = 4 waves = (2 q-halves wq) x (2 kj/d-halves grp). Q-tile 64,
// qrows/wave = 32 (2 m-frags) -> each K/V byte read feeds 2x the MFMA of R6.
// Per tile: wave(wq,grp) computes QK on kj-half grp (K-read 8KB); per-tile
// cross-wave row-max exchange via shR (so both kj-halves share one m and P
// scales are compatible); P->LDS; PV over full 32-kj tile but only d-half
// grp (V-read 8KB, accO 64 regs). l summed per kj-half, merged at end;
// accO disjoint in d -> no merge. 20KB LDS/wave/tile for 32 MFMA
// (26 FLOP/B vs R6's 15.5). LDS ~70KB -> 2 indep blocks/CU kept (R6's win).
// Defer-max kept. Grid (b=8, qt=64): one batch per XCD, KV L2-resident.
// ---------------------------------------------------------------------------
__global__ __launch_bounds__(256) void attn_kernel(
    const __bf16* __restrict__ Q, const uint8_t* __restrict__ KV,
    __bf16* __restrict__ O)
{
    const int b   = blockIdx.x;
    const int q0  = blockIdx.y * 64;
    const int tid = threadIdx.x;
    const int wv  = tid >> 6, lane = tid & 63, g = lane >> 4, n16 = lane & 15;
    const int wq  = wv & 1, grp = wv >> 1;

    __shared__ __align__(1024) uint8_t sKV[2][32768];  // dbuf 32-row KV tiles
    __shared__ __align__(1024) uint8_t sP[4096];       // P [64 q][32 kj], pair-swizzled
    __shared__ float shR[2][64];                       // per-tile rowmax exchange
    __shared__ float shL[2][64];                       // end-of-kernel l merge

    // Q fragments: 2 m-frags x 8 k-slices, rows q0 + wq*32 + m*16 + n16
    bf16x8 qf[2][8];
    #pragma unroll
    for (int m = 0; m < 2; ++m) {
        const __bf16* Qrow = Q + ((size_t)b * LSEQ + q0 + wq * 32 + m * 16 + n16) * DIN;
        #pragma unroll
        for (int ks = 0; ks < 8; ++ks)
            qf[m][ks] = *(const bf16x8*)(Qrow + ks * 32 + g * 8);
    }

    float m_i[2][4], l_i[2][4];
    #pragma unroll
    for (int m = 0; m < 2; ++m)
        #pragma unroll
        for (int r = 0; r < 4; ++r) { m_i[m][r] = -__builtin_inff(); l_i[m][r] = 0.f; }
    f32x4 accO[2][8];   // q rows (2 m) x d-half (8 ds of 16)
    #pragma unroll
    for (int m = 0; m < 2; ++m)
        #pragma unroll
        for (int ds = 0; ds < 8; ++ds) accO[m][ds] = f32x4{0.f, 0.f, 0.f, 0.f};

    const uint8_t* KVb = KV + ((size_t)b * NT2 << 15);
    const float CEXP = 1.4426950408889634f / 16.0f;   // log2(e)/scale, scale=16
    const float DEFER_TH = 88.7f;                     // 8 / CEXP

    // prologue: stage tile 0 (256 thr x 16B x 8 = 32KB)
    #pragma unroll
    for (int p = 0; p < 8; ++p) {
        const int off = p * 4096 + tid * 16;
        gload_lds16(KVb + off, &sKV[0][off]);
    }

    for (int t = 0; t < NT2; ++t) {
        const int buf = t & 1;
        if (t + 1 < NT2) {
            const uint8_t* src = KVb + ((size_t)(t + 1) << 15);
            #pragma unroll
            for (int p = 0; p < 8; ++p) {
                const int off = p * 4096 + tid * 16;
                gload_lds16(src + off, &sKV[buf ^ 1][off]);
            }
            asm volatile("s_waitcnt vmcnt(8)" ::: "memory");  // cur tile done, next in flight
        } else {
            asm volatile("s_waitcnt vmcnt(0)" ::: "memory");
        }
        __builtin_amdgcn_s_barrier();                  // B1: tile staged
        asm volatile("" ::: "memory");

        const uint8_t* kb = sKV[buf];

        // ---- QK^T on kj-half grp: S[32q x 16kj], K=256 over 8 ks ----
        f32x4 sacc[2];
        sacc[0] = f32x4{0.f, 0.f, 0.f, 0.f};
        sacc[1] = f32x4{0.f, 0.f, 0.f, 0.f};
        const int krow = grp * 16 + n16;
        __builtin_amdgcn_s_setprio(1);
        #pragma unroll
        for (int ks = 0; ks < 8; ++ks) {
            const bf16x8 kf = *(const bf16x8*)(kb + krow * 512
                               + ((ks * 64 + g * 16) ^ ((krow & 7) << 4)));
            sacc[0] = __builtin_amdgcn_mfma_f32_16x16x32_bf16(qf[0][ks], kf, sacc[0], 0, 0, 0);
            sacc[1] = __builtin_amdgcn_mfma_f32_16x16x32_bf16(qf[1][ks], kf, sacc[1], 0, 0, 0);
        }
        __builtin_amdgcn_s_setprio(0);

        // ---- own-half row max (reduce over n16 = kj) ----
        float rmx[2][4];
        #pragma unroll
        for (int m = 0; m < 2; ++m)
            #pragma unroll
            for (int r = 0; r < 4; ++r) {
                float mx = sacc[m][r];
                mx = fmaxf(mx, __shfl_xor(mx, 1));
                mx = fmaxf(mx, __shfl_xor(mx, 2));
                mx = fmaxf(mx, __shfl_xor(mx, 4));
                mx = fmaxf(mx, __shfl_xor(mx, 8));
                rmx[m][r] = mx;
            }
        if (n16 == 0) {
            #pragma unroll
            for (int m = 0; m < 2; ++m)
                #pragma unroll
                for (int r = 0; r < 4; ++r)
                    shR[grp][wq * 32 + m * 16 + g * 4 + r] = rmx[m][r];
        }
        __builtin_amdgcn_s_barrier();                  // B2: rowmax exchanged

        // ---- combined max + defer-max rescale (shared m across kj-halves) ----
        float cmb[2][4];
        float worst = -__builtin_inff();
        #pragma unroll
        for (int m = 0; m < 2; ++m)
            #pragma unroll
            for (int r = 0; r < 4; ++r) {
                const float other = shR[grp ^ 1][wq * 32 + m * 16 + g * 4 + r];
                cmb[m][r] = fmaxf(rmx[m][r], other);
                worst = fmaxf(worst, cmb[m][r] - m_i[m][r]);
            }
        if (!__all(worst <= DEFER_TH)) {
            #pragma unroll
            for (int m = 0; m < 2; ++m) {
                float scl[4];
                #pragma unroll
                for (int r = 0; r < 4; ++r) {
                    const float mnew = fmaxf(m_i[m][r], cmb[m][r]);
                    scl[r] = exp2f((m_i[m][r] - mnew) * CEXP);
                    l_i[m][r] *= scl[r];
                    m_i[m][r] = mnew;
                }
                #pragma unroll
                for (int ds = 0; ds < 8; ++ds)
                    #pragma unroll
                    for (int r = 0; r < 4; ++r)
                        accO[m][ds][r] *= scl[r];
            }
        }

        // ---- P = exp2((S-m)*c); own-half l partial; P -> LDS ----
        #pragma unroll
        for (int m = 0; m < 2; ++m)
            #pragma unroll
            for (int r = 0; r < 4; ++r) {
                const float p = exp2f((sacc[m][r] - m_i[m][r]) * CEXP);
                sacc[m][r] = p;
                float rs = p;
                rs += __shfl_xor(rs, 1);
                rs += __shfl_xor(rs, 2);
                rs += __shfl_xor(rs, 4);
                rs += __shfl_xor(rs, 8);
                l_i[m][r] += rs;
            }
        #pragma unroll
        for (int m = 0; m < 2; ++m)
            #pragma unroll
            for (int r = 0; r < 4; ++r) {
                const int row = wq * 32 + m * 16 + g * 4 + r;
                const int col = grp * 16 + n16;
                const int off = (row >> 1) * 128
                              + ((((row & 1) * 64) + 2 * col) ^ (((row >> 1) & 7) << 4));
                *(__bf16*)(sP + off) = (__bf16)sacc[m][r];
            }
        __builtin_amdgcn_s_barrier();                  // B3: P complete

        // ---- PV: full 32-kj tile, d-half grp only ----
        bf16x8 af[2];
        #pragma unroll
        for (int m = 0; m < 2; ++m) {
            const int row = wq * 32 + m * 16 + n16;
            af[m] = *(const bf16x8*)(sP + (row >> 1) * 128
                      + ((((row & 1) * 64) + g * 16) ^ (((row >> 1) & 7) << 4)));
        }
        __builtin_amdgcn_s_setprio(1);
        #pragma unroll
        for (int ds = 0; ds < 8; ++ds) {
            const int d = grp * 128 + ds * 16 + n16;
            const bf16x8 vf = *(const bf16x8*)(kb + 16384 + (d >> 1) * 128
                               + ((((d & 1) * 64) + g * 16) ^ (((d >> 1) & 7) << 4)));
            accO[0][ds] = __builtin_amdgcn_mfma_f32_16x16x32_bf16(af[0], vf, accO[0][ds], 0, 0, 0);
            accO[1][ds] = __builtin_amdgcn_mfma_f32_16x16x32_bf16(af[1], vf, accO[1][ds], 0, 0, 0);
        }
        __builtin_amdgcn_s_setprio(0);

        asm volatile("" ::: "memory");
        __builtin_amdgcn_s_barrier();                  // B4: buf + sP free
    }

    // ---- l merge across kj-halves, then write O (disjoint d columns) ----
    if (n16 == 0) {
        #pragma unroll
        for (int m = 0; m < 2; ++m)
            #pragma unroll
            for (int r = 0; r < 4; ++r)
                shL[grp][wq * 32 + m * 16 + g * 4 + r] = l_i[m][r];
    }
    __syncthreads();
    #pragma unroll
    for (int m = 0; m < 2; ++m) {
        float inv[4];
        #pragma unroll
        for (int r = 0; r < 4; ++r) {
            const float lt = l_i[m][r] + shL[grp ^ 1][wq * 32 + m * 16 + g * 4 + r];
            inv[r] = 1.f / lt;
        }
        __bf16* Ob = O + ((size_t)b * LSEQ + q0 + wq * 32 + m * 16) * DIN;
        #pragma unroll
        for (int ds = 0; ds < 8; ++ds)
            #pragma unroll
            for (int r = 0; r < 4; ++r)
                Ob[(size_t)(g * 4 + r) * DIN + grp * 128 + ds * 16 + n16] =
                    (__bf16)(accO[m][ds][r] * inv[r]);
    }
}

// ---------------------------------------------------------------------------
// Kernel 3: output projection. out[b][c][l] = sum_i Wo[c][i]*O[b][l][i] + bo[c].
// ---------------------------------------------------------------------------
__global__ __launch_bounds__(256) void out_proj_kernel(
    const float* __restrict__ Wo, const float* __restrict__ bo,
    const __bf16* __restrict__ O, float* __restrict__ out)
{
    const int b   = blockIdx.z;
    const int c0  = blockIdx.y * 64;
    const int l0  = blockIdx.x * 256;
    const int tid = threadIdx.x;
    const int wv  = tid >> 6, lane = tid & 63, g = lane >> 4, n16 = lane & 15;

    __shared__ __align__(16) __bf16 sWo[64][40];   // [c][i]
    __shared__ __align__(16) __bf16 sO[256][40];   // [l][i]

    const __bf16* Ob = O + (size_t)b * LSEQ * DIN;

    f32x4 acc[4][4];
    #pragma unroll
    for (int i = 0; i < 4; ++i)
        #pragma unroll
        for (int j = 0; j < 4; ++j)
            acc[i][j] = f32x4{0.f, 0.f, 0.f, 0.f};

    for (int kk = 0; kk < 8; ++kk) {
        const int i0 = kk * 32;
        __syncthreads();
        #pragma unroll
        for (int p = 0; p < 2; ++p) {
            const int c  = p * 32 + (tid >> 3);
            const int i4 = (tid & 7) * 4;
            const float4 v = *(const float4*)(Wo + (size_t)(c0 + c) * DIN + i0 + i4);
            bf16x4 pk = { (__bf16)v.x, (__bf16)v.y, (__bf16)v.z, (__bf16)v.w };
            *(bf16x4*)&sWo[c][i4] = pk;
        }
        #pragma unroll
        for (int p = 0; p < 4; ++p) {
            const int l  = p * 64 + (tid >> 2);
            const int sg = tid & 3;
            *(uint4*)&sO[l][sg * 8] = *(const uint4*)(Ob + (size_t)(l0 + l) * DIN + i0 + sg * 8);
        }
        __syncthreads();

        bf16x8 af[4], bfr[4];
        #pragma unroll
        for (int mr = 0; mr < 4; ++mr)
            af[mr] = *(const bf16x8*)&sWo[mr * 16 + n16][g * 8];
        #pragma unroll
        for (int nc = 0; nc < 4; ++nc)
            bfr[nc] = *(const bf16x8*)&sO[wv * 64 + nc * 16 + n16][g * 8];
        #pragma unroll
        for (int mr = 0; mr < 4; ++mr)
            #pragma unroll
            for (int nc = 0; nc < 4; ++nc)
                acc[mr][nc] = __builtin_amdgcn_mfma_f32_16x16x32_bf16(
                    af[mr], bfr[nc], acc[mr][nc], 0, 0, 0);
    }

    #pragma unroll
    for (int mr = 0; mr < 4; ++mr) {
        const int c = c0 + mr * 16 + g * 4;
        #pragma unroll
        for (int nc = 0; nc < 4; ++nc) {
            const int l = l0 + wv * 64 + nc * 16 + n16;
            #pragma unroll
            for (int r = 0; r < 4; ++r)
                out[((size_t)b * CH + c + r) * LSEQ + l] = acc[mr][nc][r] + bo[c + r];
        }
    }
}

// ---------------------------------------------------------------------------
extern "C" void kernel_launch(void* const* d_in, const int* in_sizes, int n_in,
                              void* d_out, int out_size, void* d_ws, size_t ws_size,
                              hipStream_t stream)
{
    const float* x  = (const float*)d_in[0];
    const float* Wq = (const float*)d_in[1];
    const float* bq = (const float*)d_in[2];
    const float* Wk = (const float*)d_in[3];
    const float* bk = (const float*)d_in[4];
    const float* Wv = (const float*)d_in[5];
    const float* bv = (const float*)d_in[6];
    const float* Wo = (const float*)d_in[7];
    const float* bo = (const float*)d_in[8];
    float* out = (float*)d_out;

    // ws: Q bf16 16MB | KV swizzled tile images 32MB | O bf16 16MB = 64MB
    __bf16*  Q  = (__bf16*)d_ws;
    uint8_t* KV = (uint8_t*)d_ws + (16u << 20);
    __bf16*  O  = (__bf16*)((uint8_t*)d_ws + (48u << 20));

    qkv_proj_kernel<<<dim3(LSEQ / 64, 3, BS), 256, 0, stream>>>(
        x, Wq, bq, Wk, bk, Wv, bv, Q, KV);
    attn_kernel<<<dim3(BS, LSEQ / 64), 256, 0, stream>>>(Q, KV, O);
    out_proj_kernel<<<dim3(LSEQ / 256, CH / 64, BS), 256, 0, stream>>>(Wo, bo, O, out);
}

// Round 8
// 454.343 us; speedup vs baseline: 1.4125x; 1.4125x over previous
//
#include <hip/hip_runtime.h>
#include <stdint.h>

#define BS   8
#define CH   256    // C
#define LSEQ 4096   // H*W
#define DIN  256    // INNER
#define NT2  128    // number of KV tiles (32 rows each)
#define KT2  32     // kv rows per tile

typedef __bf16 bf16x8 __attribute__((ext_vector_type(8)));
typedef __bf16 bf16x4 __attribute__((ext_vector_type(4)));
typedef float  f32x4  __attribute__((ext_vector_type(4)));

// async global->LDS, 16B per lane; LDS dest = wave-uniform base + lane*16
__device__ __forceinline__ void gload_lds16(const void* g, void* l) {
    __builtin_amdgcn_global_load_lds(
        (const __attribute__((address_space(1))) uint32_t*)g,
        (__attribute__((address_space(3))) uint32_t*)l, 16, 0, 0);
}

#define CEXP_FOLD (1.4426950408889634f / 16.0f)   // log2(e)/round(sqrt(256),2)

// ---------------------------------------------------------------------------
// Kernel 1: QKV projection. Y[l][i] = sum_c X[c][l]*W[i][c] + b[i].
// which==0 -> Q linear [l][i] bf16, PRE-SCALED by CEXP_FOLD (softmax scale
//             folded: S' = S*log2e/16, so attn uses exp2(S'-m') directly).
// which==1 -> K into swizzled tile image: tile(b,t2) 32KB, K half 16KB:
//             byte = row*512 + ((2i) ^ ((row&7)<<4)), row = l&31.
// which==2 -> V half at +16384: d-pair rows of 128B:
//             byte = 16384 + (d>>1)*128 + (((d&1)*64 + 2*(l&31)) ^ (((d>>1)&7)<<4)).
// Tile stride 32KB; base = (b*128 + t2) << 15.
// ---------------------------------------------------------------------------
__global__ __launch_bounds__(256) void qkv_proj_kernel(
    const float* __restrict__ x,
    const float* __restrict__ Wq, const float* __restrict__ bq,
    const float* __restrict__ Wk, const float* __restrict__ bk,
    const float* __restrict__ Wv, const float* __restrict__ bv,
    __bf16* __restrict__ Q, uint8_t* __restrict__ KV)
{
    const int b     = blockIdx.z;
    const int which = blockIdx.y;
    const int l0    = blockIdx.x * 64;

    const float* W    = (which == 0) ? Wq : (which == 1) ? Wk : Wv;
    const float* bias = (which == 0) ? bq : (which == 1) ? bk : bv;
    const float* X    = x + (size_t)b * CH * LSEQ;

    __shared__ __align__(16) __bf16 sXt[64][40];   // [l][c]
    __shared__ __align__(16) __bf16 sW[256][40];   // [i][c]

    const int tid  = threadIdx.x;
    const int wv   = tid >> 6;
    const int lane = tid & 63;
    const int g    = lane >> 4;
    const int n16  = lane & 15;

    f32x4 acc[4][4];
    #pragma unroll
    for (int i = 0; i < 4; ++i)
        #pragma unroll
        for (int j = 0; j < 4; ++j)
            acc[i][j] = f32x4{0.f, 0.f, 0.f, 0.f};

    for (int kk = 0; kk < 8; ++kk) {
        const int c0 = kk * 32;
        __syncthreads();
        #pragma unroll
        for (int p = 0; p < 8; ++p) {
            const int i  = p * 32 + (tid >> 3);
            const int c4 = (tid & 7) * 4;
            const float4 v = *(const float4*)(W + (size_t)i * CH + c0 + c4);
            bf16x4 pk = { (__bf16)v.x, (__bf16)v.y, (__bf16)v.z, (__bf16)v.w };
            *(bf16x4*)&sW[i][c4] = pk;
        }
        #pragma unroll
        for (int p = 0; p < 2; ++p) {
            const int c  = p * 16 + (tid >> 4);
            const int l4 = (tid & 15) * 4;
            const float4 v = *(const float4*)(X + (size_t)(c0 + c) * LSEQ + l0 + l4);
            sXt[l4 + 0][c] = (__bf16)v.x;
            sXt[l4 + 1][c] = (__bf16)v.y;
            sXt[l4 + 2][c] = (__bf16)v.z;
            sXt[l4 + 3][c] = (__bf16)v.w;
        }
        __syncthreads();

        bf16x8 af[4], bfr[4];
        #pragma unroll
        for (int mr = 0; mr < 4; ++mr)
            af[mr] = *(const bf16x8*)&sXt[mr * 16 + n16][g * 8];
        #pragma unroll
        for (int nc = 0; nc < 4; ++nc)
            bfr[nc] = *(const bf16x8*)&sW[wv * 64 + nc * 16 + n16][g * 8];
        #pragma unroll
        for (int mr = 0; mr < 4; ++mr)
            #pragma unroll
            for (int nc = 0; nc < 4; ++nc)
                acc[mr][nc] = __builtin_amdgcn_mfma_f32_16x16x32_bf16(
                    af[mr], bfr[nc], acc[mr][nc], 0, 0, 0);
    }

    // D fragment: row l = mr*16 + g*4 + r, col i = nc*16 + n16 (+wv*64)
    if (which == 0) {
        __bf16* out = Q + (size_t)b * LSEQ * DIN;
        #pragma unroll
        for (int nc = 0; nc < 4; ++nc) {
            const int icol = wv * 64 + nc * 16 + n16;
            const float bb = bias[icol];
            #pragma unroll
            for (int mr = 0; mr < 4; ++mr) {
                const int lrow = l0 + mr * 16 + g * 4;
                #pragma unroll
                for (int r = 0; r < 4; ++r)
                    out[(size_t)(lrow + r) * DIN + icol] =
                        (__bf16)((acc[mr][nc][r] + bb) * CEXP_FOLD);
            }
        }
    } else if (which == 1) {
        #pragma unroll
        for (int nc = 0; nc < 4; ++nc) {
            const int icol = wv * 64 + nc * 16 + n16;
            const float bb = bias[icol];
            #pragma unroll
            for (int mr = 0; mr < 4; ++mr) {
                #pragma unroll
                for (int r = 0; r < 4; ++r) {
                    const int lrow = l0 + mr * 16 + g * 4 + r;
                    const int t2 = lrow >> 5, row = lrow & 31;
                    const size_t off = ((size_t)(b * NT2 + t2) << 15)
                                     + (size_t)row * 512
                                     + ((icol * 2) ^ ((row & 7) << 4));
                    *(__bf16*)(KV + off) = (__bf16)(acc[mr][nc][r] + bb);
                }
            }
        }
    } else {
        #pragma unroll
        for (int nc = 0; nc < 4; ++nc) {
            const int d  = wv * 64 + nc * 16 + n16;
            const float bb = bias[d];
            #pragma unroll
            for (int mr = 0; mr < 4; ++mr) {
                const int lrow = l0 + mr * 16 + g * 4;   // 4 consecutive l (8B run)
                const int t2 = lrow >> 5, c = lrow & 31;
                bf16x4 pk;
                #pragma unroll
                for (int r = 0; r < 4; ++r)
                    pk[r] = (__bf16)(acc[mr][nc][r] + bb);
                const size_t off = ((size_t)(b * NT2 + t2) << 15) + 16384
                                 + (size_t)(d >> 1) * 128
                                 + ((((d & 1) * 64) + 2 * c) ^ (((d >> 1) & 7) << 4));
                *(bf16x4*)(KV + off) = pk;
            }
        }
    }
}

// ---------------------------------------------------------------------------
// Kernel 2: flash attention v6 — R6 structure + swapped-operand QK^T.
// 256 thr = 4 waves x 16 q-rows; KV tile 32 rows; dbuf pre-swizzled images
// staged via global_load_lds; 2 INDEPENDENT blocks/CU (R6's proven TLP).
// S^T = mfma(K-frag, Q-frag): identical kf/qf register contents, but lane
// n16 now owns one full q-column -> softmax max/sum = 7 in-reg ops + 2
// shfl_xor(16/32) instead of 32 ds_swizzles per wave-tile; m_i/l_i are
// lane scalars. P -> sP in R6's pair-swizzled layout (indices swapped);
// PV/accO/epilogue unchanged from R6, with 4 bpermutes redistributing
// scl (rare rescale) and 1/l (epilogue) to accO's row indexing.
// Defer-max in folded log2 units: threshold 8 (P <= 256, f32-safe).
// ---------------------------------------------------------------------------
__global__ __launch_bounds__(256) void attn_kernel(
    const __bf16* __restrict__ Q, const uint8_t* __restrict__ KV,
    __bf16* __restrict__ O)
{
    const int b   = blockIdx.x;
    const int q0  = blockIdx.y * 64;
    const int tid = threadIdx.x;
    const int wv  = tid >> 6, lane = tid & 63, g = lane >> 4, n16 = lane & 15;

    __shared__ __align__(1024) uint8_t sKV[2][32768];  // dbuf 32-row KV tiles
    __shared__ __align__(1024) uint8_t sP[4096];       // P [64 q][32 kj], pair-swizzled

    // Q fragments: 1 m-frag x 8 k-slices, row q0 + wv*16 + n16 (pre-scaled)
    bf16x8 qf[8];
    {
        const __bf16* Qrow = Q + ((size_t)b * LSEQ + q0 + wv * 16 + n16) * DIN;
        #pragma unroll
        for (int ks = 0; ks < 8; ++ks)
            qf[ks] = *(const bf16x8*)(Qrow + ks * 32 + g * 8);
    }

    float m_i = -__builtin_inff();   // running max for q = q0+wv*16+n16 (folded units)
    float l_i = 0.f;                 // running denom for that q
    f32x4 accO[16];
    #pragma unroll
    for (int ds = 0; ds < 16; ++ds) accO[ds] = f32x4{0.f, 0.f, 0.f, 0.f};

    const uint8_t* KVb = KV + ((size_t)b * NT2 << 15);
    const float DEFER_TH = 8.0f;     // log2 units: P bounded by 2^8

    // prologue: stage tile 0 (256 thr x 16B x 8 = 32KB)
    #pragma unroll
    for (int p = 0; p < 8; ++p) {
        const int off = p * 4096 + tid * 16;
        gload_lds16(KVb + off, &sKV[0][off]);
    }

    for (int t = 0; t < NT2; ++t) {
        const int buf = t & 1;
        if (t + 1 < NT2) {
            const uint8_t* src = KVb + ((size_t)(t + 1) << 15);
            #pragma unroll
            for (int p = 0; p < 8; ++p) {
                const int off = p * 4096 + tid * 16;
                gload_lds16(src + off, &sKV[buf ^ 1][off]);
            }
            asm volatile("s_waitcnt vmcnt(8)" ::: "memory");  // cur tile done, next in flight
        } else {
            asm volatile("s_waitcnt vmcnt(0)" ::: "memory");
        }
        __builtin_amdgcn_s_barrier();
        asm volatile("" ::: "memory");

        const uint8_t* kb = sKV[buf];

        // ---- S^T = K * Q^T : D[kj][q]; lane holds kj = nc*16+g*4+r, q = n16 ----
        f32x4 st[2];
        st[0] = f32x4{0.f, 0.f, 0.f, 0.f};
        st[1] = f32x4{0.f, 0.f, 0.f, 0.f};
        __builtin_amdgcn_s_setprio(1);
        #pragma unroll
        for (int ks = 0; ks < 8; ++ks) {
            #pragma unroll
            for (int nc = 0; nc < 2; ++nc) {
                const int row = nc * 16 + n16;   // kj row of K tile (A-frag row)
                const bf16x8 kf = *(const bf16x8*)(kb + row * 512
                                   + ((ks * 64 + g * 16) ^ ((row & 7) << 4)));
                st[nc] = __builtin_amdgcn_mfma_f32_16x16x32_bf16(kf, qf[ks], st[nc], 0, 0, 0);
            }
        }
        __builtin_amdgcn_s_setprio(0);

        // ---- softmax for q = n16: in-register over 8 kj + 2 shfl over g ----
        float mx = fmaxf(fmaxf(fmaxf(st[0][0], st[0][1]), fmaxf(st[0][2], st[0][3])),
                         fmaxf(fmaxf(st[1][0], st[1][1]), fmaxf(st[1][2], st[1][3])));
        mx = fmaxf(mx, __shfl_xor(mx, 16));
        mx = fmaxf(mx, __shfl_xor(mx, 32));
        if (!__all(mx - m_i <= DEFER_TH)) {
            const float mnew = fmaxf(m_i, mx);
            const float scl  = exp2f(m_i - mnew);
            l_i *= scl;
            m_i = mnew;
            float sclr[4];
            #pragma unroll
            for (int r = 0; r < 4; ++r)
                sclr[r] = __shfl(scl, g * 4 + r);   // scl for accO row q = g*4+r
            #pragma unroll
            for (int ds = 0; ds < 16; ++ds)
                #pragma unroll
                for (int r = 0; r < 4; ++r)
                    accO[ds][r] *= sclr[r];
        }
        float p0[4], p1[4];
        #pragma unroll
        for (int r = 0; r < 4; ++r) {
            p0[r] = exp2f(st[0][r] - m_i);
            p1[r] = exp2f(st[1][r] - m_i);
        }
        float s = ((p0[0] + p0[1]) + (p0[2] + p0[3]))
                + ((p1[0] + p1[1]) + (p1[2] + p1[3]));
        s += __shfl_xor(s, 16);
        s += __shfl_xor(s, 32);
        l_i += s;

        // ---- P -> sP[q][kj] (pair-swizzled; all kj of row q written by same wave) ----
        {
            const int prow  = wv * 16 + n16;
            const int pbase = (prow >> 1) * 128;
            const int pswz  = ((prow >> 1) & 7) << 4;
            const int phalf = (prow & 1) * 64;
            #pragma unroll
            for (int r = 0; r < 4; ++r) {
                const int c0b = 2 * (g * 4 + r);
                *(__bf16*)(sP + pbase + ((phalf + c0b) ^ pswz))      = (__bf16)p0[r];
                *(__bf16*)(sP + pbase + ((phalf + c0b + 32) ^ pswz)) = (__bf16)p1[r];
            }
        }

        // ---- PV: A = P row (n16), B = V pair-swizzled img (R6 unchanged) ----
        bf16x8 af;
        {
            const int row = wv * 16 + n16;
            af = *(const bf16x8*)(sP + (row >> 1) * 128
                   + ((((row & 1) * 64) + g * 16) ^ (((row >> 1) & 7) << 4)));
        }
        __builtin_amdgcn_s_setprio(1);
        #pragma unroll
        for (int ds = 0; ds < 16; ++ds) {
            const int d = ds * 16 + n16;
            const bf16x8 vf = *(const bf16x8*)(kb + 16384 + (d >> 1) * 128
                               + ((((d & 1) * 64) + g * 16) ^ (((d >> 1) & 7) << 4)));
            accO[ds] = __builtin_amdgcn_mfma_f32_16x16x32_bf16(af, vf, accO[ds], 0, 0, 0);
        }
        __builtin_amdgcn_s_setprio(0);

        asm volatile("" ::: "memory");
        __builtin_amdgcn_s_barrier();   // all waves done reading buf before overwrite
    }

    // ---- epilogue: O[l][d] = accO / l; redistribute 1/l to accO rows ----
    const float linv = 1.f / l_i;        // for q = n16
    float invr[4];
    #pragma unroll
    for (int r = 0; r < 4; ++r)
        invr[r] = __shfl(linv, g * 4 + r);
    __bf16* Ob = O + ((size_t)b * LSEQ + q0 + wv * 16) * DIN;
    #pragma unroll
    for (int ds = 0; ds < 16; ++ds)
        #pragma unroll
        for (int r = 0; r < 4; ++r)
            Ob[(size_t)(g * 4 + r) * DIN + ds * 16 + n16] = (__bf16)(accO[ds][r] * invr[r]);
}

// ---------------------------------------------------------------------------
// Kernel 3: output projection. out[b][c][l] = sum_i Wo[c][i]*O[b][l][i] + bo[c].
// ---------------------------------------------------------------------------
__global__ __launch_bounds__(256) void out_proj_kernel(
    const float* __restrict__ Wo, const float* __restrict__ bo,
    const __bf16* __restrict__ O, float* __restrict__ out)
{
    const int b   = blockIdx.z;
    const int c0  = blockIdx.y * 64;
    const int l0  = blockIdx.x * 256;
    const int tid = threadIdx.x;
    const int wv  = tid >> 6, lane = tid & 63, g = lane >> 4, n16 = lane & 15;

    __shared__ __align__(16) __bf16 sWo[64][40];   // [c][i]
    __shared__ __align__(16) __bf16 sO[256][40];   // [l][i]

    const __bf16* Ob = O + (size_t)b * LSEQ * DIN;

    f32x4 acc[4][4];
    #pragma unroll
    for (int i = 0; i < 4; ++i)
        #pragma unroll
        for (int j = 0; j < 4; ++j)
            acc[i][j] = f32x4{0.f, 0.f, 0.f, 0.f};

    for (int kk = 0; kk < 8; ++kk) {
        const int i0 = kk * 32;
        __syncthreads();
        #pragma unroll
        for (int p = 0; p < 2; ++p) {
            const int c  = p * 32 + (tid >> 3);
            const int i4 = (tid & 7) * 4;
            const float4 v = *(const float4*)(Wo + (size_t)(c0 + c) * DIN + i0 + i4);
            bf16x4 pk = { (__bf16)v.x, (__bf16)v.y, (__bf16)v.z, (__bf16)v.w };
            *(bf16x4*)&sWo[c][i4] = pk;
        }
        #pragma unroll
        for (int p = 0; p < 4; ++p) {
            const int l  = p * 64 + (tid >> 2);
            const int sg = tid & 3;
            *(uint4*)&sO[l][sg * 8] = *(const uint4*)(Ob + (size_t)(l0 + l) * DIN + i0 + sg * 8);
        }
        __syncthreads();

        bf16x8 af[4], bfr[4];
        #pragma unroll
        for (int mr = 0; mr < 4; ++mr)
            af[mr] = *(const bf16x8*)&sWo[mr * 16 + n16][g * 8];
        #pragma unroll
        for (int nc = 0; nc < 4; ++nc)
            bfr[nc] = *(const bf16x8*)&sO[wv * 64 + nc * 16 + n16][g * 8];
        #pragma unroll
        for (int mr = 0; mr < 4; ++mr)
            #pragma unroll
            for (int nc = 0; nc < 4; ++nc)
                acc[mr][nc] = __builtin_amdgcn_mfma_f32_16x16x32_bf16(
                    af[mr], bfr[nc], acc[mr][nc], 0, 0, 0);
    }

    #pragma unroll
    for (int mr = 0; mr < 4; ++mr) {
        const int c = c0 + mr * 16 + g * 4;
        #pragma unroll
        for (int nc = 0; nc < 4; ++nc) {
            const int l = l0 + wv * 64 + nc * 16 + n16;
            #pragma unroll
            for (int r = 0; r < 4; ++r)
                out[((size_t)b * CH + c + r) * LSEQ + l] = acc[mr][nc][r] + bo[c + r];
        }
    }
}

// ---------------------------------------------------------------------------
extern "C" void kernel_launch(void* const* d_in, const int* in_sizes, int n_in,
                              void* d_out, int out_size, void* d_ws, size_t ws_size,
                              hipStream_t stream)
{
    const float* x  = (const float*)d_in[0];
    const float* Wq = (const float*)d_in[1];
    const float* bq = (const float*)d_in[2];
    const float* Wk = (const float*)d_in[3];
    const float* bk = (const float*)d_in[4];
    const float* Wv = (const float*)d_in[5];
    const float* bv = (const float*)d_in[6];
    const float* Wo = (const float*)d_in[7];
    const float* bo = (const float*)d_in[8];
    float* out = (float*)d_out;

    // ws: Q bf16 16MB | KV swizzled tile images 32MB | O bf16 16MB = 64MB
    __bf16*  Q  = (__bf16*)d_ws;
    uint8_t* KV = (uint8_t*)d_ws + (16u << 20);
    __bf16*  O  = (__bf16*)((uint8_t*)d_ws + (48u << 20));

    qkv_proj_kernel<<<dim3(LSEQ / 64, 3, BS), 256, 0, stream>>>(
        x, Wq, bq, Wk, bk, Wv, bv, Q, KV);
    attn_kernel<<<dim3(BS, LSEQ / 64), 256, 0, stream>>>(Q, KV, O);
    out_proj_kernel<<<dim3(LSEQ / 256, CH / 64, BS), 256, 0, stream>>>(Wo, bo, O, out);
}

// Round 9
// 310.139 us; speedup vs baseline: 2.0692x; 1.4650x over previous
//
#include <hip/hip_runtime.h>
#include <stdint.h>

#define BS   8
#define CH   256    // C
#define LSEQ 4096   // H*W
#define DIN  256    // INNER
#define NT2  128    // number of KV tiles (32 rows each)
#define KT2  32     // kv rows per tile

typedef __bf16 bf16x8 __attribute__((ext_vector_type(8)));
typedef __bf16 bf16x4 __attribute__((ext_vector_type(4)));
typedef float  f32x4  __attribute__((ext_vector_type(4)));

// async global->LDS, 16B per lane; LDS dest = wave-uniform base + lane*16
__device__ __forceinline__ void gload_lds16(const void* g, void* l) {
    __builtin_amdgcn_global_load_lds(
        (const __attribute__((address_space(1))) uint32_t*)g,
        (__attribute__((address_space(3))) uint32_t*)l, 16, 0, 0);
}

#define CEXP_FOLD (1.4426950408889634f / 16.0f)   // log2(e)/round(sqrt(256),2)

// ---------------------------------------------------------------------------
// Kernel 1: QKV projection. Y[l][i] = sum_c X[c][l]*W[i][c] + b[i].
// which==0 -> Q linear [l][i] bf16, PRE-SCALED by CEXP_FOLD (log2-folded
//             softmax scale; attn computes exp2(S'-m') directly).
// which==1 -> K into swizzled tile image: tile(b,t2) 32KB, K half 16KB:
//             byte = row*512 + ((2i) ^ ((row&7)<<4)), row = l&31.
// which==2 -> V half at +16384: d-pair rows of 128B:
//             byte = 16384 + (d>>1)*128 + (((d&1)*64 + 2*(l&31)) ^ (((d>>1)&7)<<4)).
// Tile stride 32KB; base = (b*128 + t2) << 15.
// ---------------------------------------------------------------------------
__global__ __launch_bounds__(256) void qkv_proj_kernel(
    const float* __restrict__ x,
    const float* __restrict__ Wq, const float* __restrict__ bq,
    const float* __restrict__ Wk, const float* __restrict__ bk,
    const float* __restrict__ Wv, const float* __restrict__ bv,
    __bf16* __restrict__ Q, uint8_t* __restrict__ KV)
{
    const int b     = blockIdx.z;
    const int which = blockIdx.y;
    const int l0    = blockIdx.x * 64;

    const float* W    = (which == 0) ? Wq : (which == 1) ? Wk : Wv;
    const float* bias = (which == 0) ? bq : (which == 1) ? bk : bv;
    const float* X    = x + (size_t)b * CH * LSEQ;

    __shared__ __align__(16) __bf16 sXt[64][40];   // [l][c]
    __shared__ __align__(16) __bf16 sW[256][40];   // [i][c]

    const int tid  = threadIdx.x;
    const int wv   = tid >> 6;
    const int lane = tid & 63;
    const int g    = lane >> 4;
    const int n16  = lane & 15;

    f32x4 acc[4][4];
    #pragma unroll
    for (int i = 0; i < 4; ++i)
        #pragma unroll
        for (int j = 0; j < 4; ++j)
            acc[i][j] = f32x4{0.f, 0.f, 0.f, 0.f};

    for (int kk = 0; kk < 8; ++kk) {
        const int c0 = kk * 32;
        __syncthreads();
        #pragma unroll
        for (int p = 0; p < 8; ++p) {
            const int i  = p * 32 + (tid >> 3);
            const int c4 = (tid & 7) * 4;
            const float4 v = *(const float4*)(W + (size_t)i * CH + c0 + c4);
            bf16x4 pk = { (__bf16)v.x, (__bf16)v.y, (__bf16)v.z, (__bf16)v.w };
            *(bf16x4*)&sW[i][c4] = pk;
        }
        #pragma unroll
        for (int p = 0; p < 2; ++p) {
            const int c  = p * 16 + (tid >> 4);
            const int l4 = (tid & 15) * 4;
            const float4 v = *(const float4*)(X + (size_t)(c0 + c) * LSEQ + l0 + l4);
            sXt[l4 + 0][c] = (__bf16)v.x;
            sXt[l4 + 1][c] = (__bf16)v.y;
            sXt[l4 + 2][c] = (__bf16)v.z;
            sXt[l4 + 3][c] = (__bf16)v.w;
        }
        __syncthreads();

        bf16x8 af[4], bfr[4];
        #pragma unroll
        for (int mr = 0; mr < 4; ++mr)
            af[mr] = *(const bf16x8*)&sXt[mr * 16 + n16][g * 8];
        #pragma unroll
        for (int nc = 0; nc < 4; ++nc)
            bfr[nc] = *(const bf16x8*)&sW[wv * 64 + nc * 16 + n16][g * 8];
        #pragma unroll
        for (int mr = 0; mr < 4; ++mr)
            #pragma unroll
            for (int nc = 0; nc < 4; ++nc)
                acc[mr][nc] = __builtin_amdgcn_mfma_f32_16x16x32_bf16(
                    af[mr], bfr[nc], acc[mr][nc], 0, 0, 0);
    }

    // D fragment: row l = mr*16 + g*4 + r, col i = nc*16 + n16 (+wv*64)
    if (which == 0) {
        __bf16* out = Q + (size_t)b * LSEQ * DIN;
        #pragma unroll
        for (int nc = 0; nc < 4; ++nc) {
            const int icol = wv * 64 + nc * 16 + n16;
            const float bb = bias[icol];
            #pragma unroll
            for (int mr = 0; mr < 4; ++mr) {
                const int lrow = l0 + mr * 16 + g * 4;
                #pragma unroll
                for (int r = 0; r < 4; ++r)
                    out[(size_t)(lrow + r) * DIN + icol] =
                        (__bf16)((acc[mr][nc][r] + bb) * CEXP_FOLD);
            }
        }
    } else if (which == 1) {
        #pragma unroll
        for (int nc = 0; nc < 4; ++nc) {
            const int icol = wv * 64 + nc * 16 + n16;
            const float bb = bias[icol];
            #pragma unroll
            for (int mr = 0; mr < 4; ++mr) {
                #pragma unroll
                for (int r = 0; r < 4; ++r) {
                    const int lrow = l0 + mr * 16 + g * 4 + r;
                    const int t2 = lrow >> 5, row = lrow & 31;
                    const size_t off = ((size_t)(b * NT2 + t2) << 15)
                                     + (size_t)row * 512
                                     + ((icol * 2) ^ ((row & 7) << 4));
                    *(__bf16*)(KV + off) = (__bf16)(acc[mr][nc][r] + bb);
                }
            }
        }
    } else {
        #pragma unroll
        for (int nc = 0; nc < 4; ++nc) {
            const int d  = wv * 64 + nc * 16 + n16;
            const float bb = bias[d];
            #pragma unroll
            for (int mr = 0; mr < 4; ++mr) {
                const int lrow = l0 + mr * 16 + g * 4;   // 4 consecutive l (8B run)
                const int t2 = lrow >> 5, c = lrow & 31;
                bf16x4 pk;
                #pragma unroll
                for (int r = 0; r < 4; ++r)
                    pk[r] = (__bf16)(acc[mr][nc][r] + bb);
                const size_t off = ((size_t)(b * NT2 + t2) << 15) + 16384
                                 + (size_t)(d >> 1) * 128
                                 + ((((d & 1) * 64) + 2 * c) ^ (((d >> 1) & 7) << 4));
                *(bf16x4*)(KV + off) = pk;
            }
        }
    }
}

// ---------------------------------------------------------------------------
// Kernel 2: flash attention v7 — R6 structure (proven 315us, 2 indep
// blocks/CU) + three register-neutral cuts:
//  (1) denominator via ones-MFMA: accL = mfma(P, ones, accL) — replaces the
//      16 sum-shuffles/tile; epilogue 1/accL[r] needs no redistribution.
//  (2) Q pre-scaled (log2-folded): exp2(sacc - m) directly, no *CEXP.
//  (3) s_setprio(1) around MFMA clusters (T5).
// Everything else IDENTICAL to R6 (unswapped QK^T, 16 q-rows/wave, KV tile
// 32 rows, dbuf pre-swizzled images, gload_lds, counted vmcnt, defer-max).
// R7/R8 lesson: keep combined VGPR+AGPR <= ~190 or lose 2nd block/CU.
// ---------------------------------------------------------------------------
__global__ __launch_bounds__(256) void attn_kernel(
    const __bf16* __restrict__ Q, const uint8_t* __restrict__ KV,
    __bf16* __restrict__ O)
{
    const int b   = blockIdx.x;
    const int q0  = blockIdx.y * 64;
    const int tid = threadIdx.x;
    const int wv  = tid >> 6, lane = tid & 63, g = lane >> 4, n16 = lane & 15;

    __shared__ __align__(1024) uint8_t sKV[2][32768];  // dbuf 32-row KV tiles
    __shared__ __align__(1024) uint8_t sP[4096];       // P [64 q][32 kj], pair-swizzled

    // Q fragments: 1 m-frag x 8 k-slices, row q0 + wv*16 + n16 (pre-scaled)
    bf16x8 qf[8];
    {
        const __bf16* Qrow = Q + ((size_t)b * LSEQ + q0 + wv * 16 + n16) * DIN;
        #pragma unroll
        for (int ks = 0; ks < 8; ++ks)
            qf[ks] = *(const bf16x8*)(Qrow + ks * 32 + g * 8);
    }

    // constant ones B-fragment (layout-invariant for all-equal values)
    bf16x8 onesf;
    #pragma unroll
    for (int j = 0; j < 8; ++j) onesf[j] = (__bf16)1.0f;

    float m_i[4];
    #pragma unroll
    for (int r = 0; r < 4; ++r) m_i[r] = -__builtin_inff();
    f32x4 accO[16];
    #pragma unroll
    for (int ds = 0; ds < 16; ++ds) accO[ds] = f32x4{0.f, 0.f, 0.f, 0.f};
    f32x4 accL = f32x4{0.f, 0.f, 0.f, 0.f};   // denominator rows g*4+r

    const uint8_t* KVb = KV + ((size_t)b * NT2 << 15);
    const float DEFER_TH = 8.0f;   // log2 units: P bounded by 2^8

    // prologue: stage tile 0 (256 thr x 16B x 8 = 32KB)
    #pragma unroll
    for (int p = 0; p < 8; ++p) {
        const int off = p * 4096 + tid * 16;
        gload_lds16(KVb + off, &sKV[0][off]);
    }

    for (int t = 0; t < NT2; ++t) {
        const int buf = t & 1;
        if (t + 1 < NT2) {
            const uint8_t* src = KVb + ((size_t)(t + 1) << 15);
            #pragma unroll
            for (int p = 0; p < 8; ++p) {
                const int off = p * 4096 + tid * 16;
                gload_lds16(src + off, &sKV[buf ^ 1][off]);
            }
            asm volatile("s_waitcnt vmcnt(8)" ::: "memory");  // cur tile done, next in flight
        } else {
            asm volatile("s_waitcnt vmcnt(0)" ::: "memory");
        }
        __builtin_amdgcn_s_barrier();
        asm volatile("" ::: "memory");

        const uint8_t* kb = sKV[buf];

        // ---- QK^T: D[qi][kj], 32 kj (2 nc frags), K=256 over 8 ks ----
        f32x4 sacc[2];
        sacc[0] = f32x4{0.f, 0.f, 0.f, 0.f};
        sacc[1] = f32x4{0.f, 0.f, 0.f, 0.f};
        __builtin_amdgcn_s_setprio(1);
        #pragma unroll
        for (int ks = 0; ks < 8; ++ks) {
            #pragma unroll
            for (int nc = 0; nc < 2; ++nc) {
                const int row = nc * 16 + n16;
                const bf16x8 kf = *(const bf16x8*)(kb + row * 512
                                   + ((ks * 64 + g * 16) ^ ((row & 7) << 4)));
                sacc[nc] = __builtin_amdgcn_mfma_f32_16x16x32_bf16(qf[ks], kf, sacc[nc], 0, 0, 0);
            }
        }
        __builtin_amdgcn_s_setprio(0);

        // ---- online max with defer; lane rows g*4+r (folded log2 units) ----
        float rmax[4];
        float worst = -__builtin_inff();
        #pragma unroll
        for (int r = 0; r < 4; ++r) {
            float mx = fmaxf(sacc[0][r], sacc[1][r]);
            mx = fmaxf(mx, __shfl_xor(mx, 1));
            mx = fmaxf(mx, __shfl_xor(mx, 2));
            mx = fmaxf(mx, __shfl_xor(mx, 4));
            mx = fmaxf(mx, __shfl_xor(mx, 8));
            rmax[r] = mx;
            worst = fmaxf(worst, mx - m_i[r]);
        }
        if (!__all(worst <= DEFER_TH)) {
            float scl[4];
            #pragma unroll
            for (int r = 0; r < 4; ++r) {
                const float mnew = fmaxf(m_i[r], rmax[r]);
                scl[r] = exp2f(m_i[r] - mnew);
                m_i[r] = mnew;
            }
            #pragma unroll
            for (int ds = 0; ds < 16; ++ds)
                #pragma unroll
                for (int r = 0; r < 4; ++r)
                    accO[ds][r] *= scl[r];
            #pragma unroll
            for (int r = 0; r < 4; ++r)
                accL[r] *= scl[r];
        }
        // P = exp2(S' - m); no sum-shuffles (denominator via ones-MFMA below)
        #pragma unroll
        for (int r = 0; r < 4; ++r) {
            sacc[0][r] = exp2f(sacc[0][r] - m_i[r]);
            sacc[1][r] = exp2f(sacc[1][r] - m_i[r]);
        }

        // ---- P -> LDS (wave-private rows; pair-swizzled 128B rows) ----
        #pragma unroll
        for (int r = 0; r < 4; ++r) {
            const int row = wv * 16 + g * 4 + r;
            #pragma unroll
            for (int nc = 0; nc < 2; ++nc) {
                const int col = nc * 16 + n16;
                const int off = (row >> 1) * 128
                              + ((((row & 1) * 64) + 2 * col) ^ (((row >> 1) & 7) << 4));
                *(__bf16*)(sP + off) = (__bf16)sacc[nc][r];
            }
        }

        // ---- PV: A = P row (n16), B = V pair-swizzled img; +ones-MFMA for l ----
        bf16x8 af;
        {
            const int row = wv * 16 + n16;
            af = *(const bf16x8*)(sP + (row >> 1) * 128
                   + ((((row & 1) * 64) + g * 16) ^ (((row >> 1) & 7) << 4)));
        }
        __builtin_amdgcn_s_setprio(1);
        #pragma unroll
        for (int ds = 0; ds < 16; ++ds) {
            const int d = ds * 16 + n16;
            const bf16x8 vf = *(const bf16x8*)(kb + 16384 + (d >> 1) * 128
                               + ((((d & 1) * 64) + g * 16) ^ (((d >> 1) & 7) << 4)));
            accO[ds] = __builtin_amdgcn_mfma_f32_16x16x32_bf16(af, vf, accO[ds], 0, 0, 0);
        }
        accL = __builtin_amdgcn_mfma_f32_16x16x32_bf16(af, onesf, accL, 0, 0, 0);
        __builtin_amdgcn_s_setprio(0);

        asm volatile("" ::: "memory");
        __builtin_amdgcn_s_barrier();   // all waves done reading buf before overwrite
    }

    // ---- epilogue: O[l][d] = accO / accL (rows already aligned) ----
    float inv[4];
    #pragma unroll
    for (int r = 0; r < 4; ++r) inv[r] = 1.f / accL[r];
    __bf16* Ob = O + ((size_t)b * LSEQ + q0 + wv * 16) * DIN;
    #pragma unroll
    for (int ds = 0; ds < 16; ++ds)
        #pragma unroll
        for (int r = 0; r < 4; ++r)
            Ob[(size_t)(g * 4 + r) * DIN + ds * 16 + n16] = (__bf16)(accO[ds][r] * inv[r]);
}

// ---------------------------------------------------------------------------
// Kernel 3: output projection. out[b][c][l] = sum_i Wo[c][i]*O[b][l][i] + bo[c].
// ---------------------------------------------------------------------------
__global__ __launch_bounds__(256) void out_proj_kernel(
    const float* __restrict__ Wo, const float* __restrict__ bo,
    const __bf16* __restrict__ O, float* __restrict__ out)
{
    const int b   = blockIdx.z;
    const int c0  = blockIdx.y * 64;
    const int l0  = blockIdx.x * 256;
    const int tid = threadIdx.x;
    const int wv  = tid >> 6, lane = tid & 63, g = lane >> 4, n16 = lane & 15;

    __shared__ __align__(16) __bf16 sWo[64][40];   // [c][i]
    __shared__ __align__(16) __bf16 sO[256][40];   // [l][i]

    const __bf16* Ob = O + (size_t)b * LSEQ * DIN;

    f32x4 acc[4][4];
    #pragma unroll
    for (int i = 0; i < 4; ++i)
        #pragma unroll
        for (int j = 0; j < 4; ++j)
            acc[i][j] = f32x4{0.f, 0.f, 0.f, 0.f};

    for (int kk = 0; kk < 8; ++kk) {
        const int i0 = kk * 32;
        __syncthreads();
        #pragma unroll
        for (int p = 0; p < 2; ++p) {
            const int c  = p * 32 + (tid >> 3);
            const int i4 = (tid & 7) * 4;
            const float4 v = *(const float4*)(Wo + (size_t)(c0 + c) * DIN + i0 + i4);
            bf16x4 pk = { (__bf16)v.x, (__bf16)v.y, (__bf16)v.z, (__bf16)v.w };
            *(bf16x4*)&sWo[c][i4] = pk;
        }
        #pragma unroll
        for (int p = 0; p < 4; ++p) {
            const int l  = p * 64 + (tid >> 2);
            const int sg = tid & 3;
            *(uint4*)&sO[l][sg * 8] = *(const uint4*)(Ob + (size_t)(l0 + l) * DIN + i0 + sg * 8);
        }
        __syncthreads();

        bf16x8 af[4], bfr[4];
        #pragma unroll
        for (int mr = 0; mr < 4; ++mr)
            af[mr] = *(const bf16x8*)&sWo[mr * 16 + n16][g * 8];
        #pragma unroll
        for (int nc = 0; nc < 4; ++nc)
            bfr[nc] = *(const bf16x8*)&sO[wv * 64 + nc * 16 + n16][g * 8];
        #pragma unroll
        for (int mr = 0; mr < 4; ++mr)
            #pragma unroll
            for (int nc = 0; nc < 4; ++nc)
                acc[mr][nc] = __builtin_amdgcn_mfma_f32_16x16x32_bf16(
                    af[mr], bfr[nc], acc[mr][nc], 0, 0, 0);
    }

    #pragma unroll
    for (int mr = 0; mr < 4; ++mr) {
        const int c = c0 + mr * 16 + g * 4;
        #pragma unroll
        for (int nc = 0; nc < 4; ++nc) {
            const int l = l0 + wv * 64 + nc * 16 + n16;
            #pragma unroll
            for (int r = 0; r < 4; ++r)
                out[((size_t)b * CH + c + r) * LSEQ + l] = acc[mr][nc][r] + bo[c + r];
        }
    }
}

// ---------------------------------------------------------------------------
extern "C" void kernel_launch(void* const* d_in, const int* in_sizes, int n_in,
                              void* d_out, int out_size, void* d_ws, size_t ws_size,
                              hipStream_t stream)
{
    const float* x  = (const float*)d_in[0];
    const float* Wq = (const float*)d_in[1];
    const float* bq = (const float*)d_in[2];
    const float* Wk = (const float*)d_in[3];
    const float* bk = (const float*)d_in[4];
    const float* Wv = (const float*)d_in[5];
    const float* bv = (const float*)d_in[6];
    const float* Wo = (const float*)d_in[7];
    const float* bo = (const float*)d_in[8];
    float* out = (float*)d_out;

    // ws: Q bf16 16MB | KV swizzled tile images 32MB | O bf16 16MB = 64MB
    __bf16*  Q  = (__bf16*)d_ws;
    uint8_t* KV = (uint8_t*)d_ws + (16u << 20);
    __bf16*  O  = (__bf16*)((uint8_t*)d_ws + (48u << 20));

    qkv_proj_kernel<<<dim3(LSEQ / 64, 3, BS), 256, 0, stream>>>(
        x, Wq, bq, Wk, bk, Wv, bv, Q, KV);
    attn_kernel<<<dim3(BS, LSEQ / 64), 256, 0, stream>>>(Q, KV, O);
    out_proj_kernel<<<dim3(LSEQ / 256, CH / 64, BS), 256, 0, stream>>>(Wo, bo, O, out);
}

// Round 10
// 262.881 us; speedup vs baseline: 2.4412x; 1.1798x over previous
//
#include <hip/hip_runtime.h>
#include <stdint.h>

#define BS   8
#define CH   256    // C
#define LSEQ 4096   // H*W
#define DIN  256    // INNER
#define NT2  128    // number of KV tiles (32 rows each)
#define KT2  32     // kv rows per tile

typedef __bf16 bf16x8 __attribute__((ext_vector_type(8)));
typedef __bf16 bf16x4 __attribute__((ext_vector_type(4)));
typedef float  f32x4  __attribute__((ext_vector_type(4)));

// async global->LDS, 16B per lane; LDS dest = wave-uniform base + lane*16
__device__ __forceinline__ void gload_lds16(const void* g, void* l) {
    __builtin_amdgcn_global_load_lds(
        (const __attribute__((address_space(1))) uint32_t*)g,
        (__attribute__((address_space(3))) uint32_t*)l, 16, 0, 0);
}

#define CEXP_FOLD (1.4426950408889634f / 16.0f)   // log2(e)/round(sqrt(256),2)

// ---------------------------------------------------------------------------
// Kernel 1: QKV projection. Y[l][i] = sum_c X[c][l]*W[i][c] + b[i].
// which==0 -> Q linear [l][i] bf16, PRE-SCALED by CEXP_FOLD (log2-folded
//             softmax scale; attn computes exp2(S'-m') directly).
// which==1 -> K into swizzled tile image: tile(b,t2) 32KB, K half 16KB:
//             byte = row*512 + ((2i) ^ ((row&7)<<4)), row = l&31.
// which==2 -> V half at +16384: d-pair rows of 128B:
//             byte = 16384 + (d>>1)*128 + (((d&1)*64 + 2*(l&31)) ^ (((d>>1)&7)<<4)).
// Tile stride 32KB; base = (b*128 + t2) << 15.
// ---------------------------------------------------------------------------
__global__ __launch_bounds__(256) void qkv_proj_kernel(
    const float* __restrict__ x,
    const float* __restrict__ Wq, const float* __restrict__ bq,
    const float* __restrict__ Wk, const float* __restrict__ bk,
    const float* __restrict__ Wv, const float* __restrict__ bv,
    __bf16* __restrict__ Q, uint8_t* __restrict__ KV)
{
    const int b     = blockIdx.z;
    const int which = blockIdx.y;
    const int l0    = blockIdx.x * 64;

    const float* W    = (which == 0) ? Wq : (which == 1) ? Wk : Wv;
    const float* bias = (which == 0) ? bq : (which == 1) ? bk : bv;
    const float* X    = x + (size_t)b * CH * LSEQ;

    __shared__ __align__(16) __bf16 sXt[64][40];   // [l][c]
    __shared__ __align__(16) __bf16 sW[256][40];   // [i][c]

    const int tid  = threadIdx.x;
    const int wv   = tid >> 6;
    const int lane = tid & 63;
    const int g    = lane >> 4;
    const int n16  = lane & 15;

    f32x4 acc[4][4];
    #pragma unroll
    for (int i = 0; i < 4; ++i)
        #pragma unroll
        for (int j = 0; j < 4; ++j)
            acc[i][j] = f32x4{0.f, 0.f, 0.f, 0.f};

    for (int kk = 0; kk < 8; ++kk) {
        const int c0 = kk * 32;
        __syncthreads();
        #pragma unroll
        for (int p = 0; p < 8; ++p) {
            const int i  = p * 32 + (tid >> 3);
            const int c4 = (tid & 7) * 4;
            const float4 v = *(const float4*)(W + (size_t)i * CH + c0 + c4);
            bf16x4 pk = { (__bf16)v.x, (__bf16)v.y, (__bf16)v.z, (__bf16)v.w };
            *(bf16x4*)&sW[i][c4] = pk;
        }
        #pragma unroll
        for (int p = 0; p < 2; ++p) {
            const int c  = p * 16 + (tid >> 4);
            const int l4 = (tid & 15) * 4;
            const float4 v = *(const float4*)(X + (size_t)(c0 + c) * LSEQ + l0 + l4);
            sXt[l4 + 0][c] = (__bf16)v.x;
            sXt[l4 + 1][c] = (__bf16)v.y;
            sXt[l4 + 2][c] = (__bf16)v.z;
            sXt[l4 + 3][c] = (__bf16)v.w;
        }
        __syncthreads();

        bf16x8 af[4], bfr[4];
        #pragma unroll
        for (int mr = 0; mr < 4; ++mr)
            af[mr] = *(const bf16x8*)&sXt[mr * 16 + n16][g * 8];
        #pragma unroll
        for (int nc = 0; nc < 4; ++nc)
            bfr[nc] = *(const bf16x8*)&sW[wv * 64 + nc * 16 + n16][g * 8];
        #pragma unroll
        for (int mr = 0; mr < 4; ++mr)
            #pragma unroll
            for (int nc = 0; nc < 4; ++nc)
                acc[mr][nc] = __builtin_amdgcn_mfma_f32_16x16x32_bf16(
                    af[mr], bfr[nc], acc[mr][nc], 0, 0, 0);
    }

    // D fragment: row l = mr*16 + g*4 + r, col i = nc*16 + n16 (+wv*64)
    if (which == 0) {
        __bf16* out = Q + (size_t)b * LSEQ * DIN;
        #pragma unroll
        for (int nc = 0; nc < 4; ++nc) {
            const int icol = wv * 64 + nc * 16 + n16;
            const float bb = bias[icol];
            #pragma unroll
            for (int mr = 0; mr < 4; ++mr) {
                const int lrow = l0 + mr * 16 + g * 4;
                #pragma unroll
                for (int r = 0; r < 4; ++r)
                    out[(size_t)(lrow + r) * DIN + icol] =
                        (__bf16)((acc[mr][nc][r] + bb) * CEXP_FOLD);
            }
        }
    } else if (which == 1) {
        #pragma unroll
        for (int nc = 0; nc < 4; ++nc) {
            const int icol = wv * 64 + nc * 16 + n16;
            const float bb = bias[icol];
            #pragma unroll
            for (int mr = 0; mr < 4; ++mr) {
                #pragma unroll
                for (int r = 0; r < 4; ++r) {
                    const int lrow = l0 + mr * 16 + g * 4 + r;
                    const int t2 = lrow >> 5, row = lrow & 31;
                    const size_t off = ((size_t)(b * NT2 + t2) << 15)
                                     + (size_t)row * 512
                                     + ((icol * 2) ^ ((row & 7) << 4));
                    *(__bf16*)(KV + off) = (__bf16)(acc[mr][nc][r] + bb);
                }
            }
        }
    } else {
        #pragma unroll
        for (int nc = 0; nc < 4; ++nc) {
            const int d  = wv * 64 + nc * 16 + n16;
            const float bb = bias[d];
            #pragma unroll
            for (int mr = 0; mr < 4; ++mr) {
                const int lrow = l0 + mr * 16 + g * 4;   // 4 consecutive l (8B run)
                const int t2 = lrow >> 5, c = lrow & 31;
                bf16x4 pk;
                #pragma unroll
                for (int r = 0; r < 4; ++r)
                    pk[r] = (__bf16)(acc[mr][nc][r] + bb);
                const size_t off = ((size_t)(b * NT2 + t2) << 15) + 16384
                                 + (size_t)(d >> 1) * 128
                                 + ((((d & 1) * 64) + 2 * c) ^ (((d >> 1) & 7) << 4));
                *(bf16x4*)(KV + off) = pk;
            }
        }
    }
}

// ---------------------------------------------------------------------------
// Kernel 2: flash attention v8 — R9 + swapped-operand QK^T at R9's register
// budget. st = mfma(kf, qf): same LDS reads/MFMA count, but lane n16 owns a
// full q-column -> softmax max = 7 in-reg fmax + 2 shfl (was 16 shfl + 8
// fmax); m_i is one scalar (was 4). R8's +12 VGPR removed by: packed bf16x4
// P-stores (2 ds_writes, 8B runs never cross the 16B swizzle granule),
// ones-MFMA accL (epilogue row-aligned, no shuffles), scl redistribution
// only inside the rare rescale branch.
// Everything else IDENTICAL to R9 (16 q-rows/wave, KV tile 32, dbuf
// pre-swizzled images, gload_lds, counted vmcnt, defer-max, setprio,
// 2 independent blocks/CU). Cliff rule: combined VGPR+AGPR <= ~196.
// ---------------------------------------------------------------------------
__global__ __launch_bounds__(256) void attn_kernel(
    const __bf16* __restrict__ Q, const uint8_t* __restrict__ KV,
    __bf16* __restrict__ O)
{
    const int b   = blockIdx.x;
    const int q0  = blockIdx.y * 64;
    const int tid = threadIdx.x;
    const int wv  = tid >> 6, lane = tid & 63, g = lane >> 4, n16 = lane & 15;

    __shared__ __align__(1024) uint8_t sKV[2][32768];  // dbuf 32-row KV tiles
    __shared__ __align__(1024) uint8_t sP[4096];       // P [64 q][32 kj], pair-swizzled

    // Q fragments (pre-scaled): row q0 + wv*16 + n16; used as mfma B-operand
    bf16x8 qf[8];
    {
        const __bf16* Qrow = Q + ((size_t)b * LSEQ + q0 + wv * 16 + n16) * DIN;
        #pragma unroll
        for (int ks = 0; ks < 8; ++ks)
            qf[ks] = *(const bf16x8*)(Qrow + ks * 32 + g * 8);
    }

    // constant ones B-fragment (layout-invariant for all-equal values)
    bf16x8 onesf;
    #pragma unroll
    for (int j = 0; j < 8; ++j) onesf[j] = (__bf16)1.0f;

    float m_i = -__builtin_inff();   // running max for q = q0+wv*16+n16 (log2 units)
    f32x4 accO[16];
    #pragma unroll
    for (int ds = 0; ds < 16; ++ds) accO[ds] = f32x4{0.f, 0.f, 0.f, 0.f};
    f32x4 accL = f32x4{0.f, 0.f, 0.f, 0.f};   // denominator, rows g*4+r

    const uint8_t* KVb = KV + ((size_t)b * NT2 << 15);
    const float DEFER_TH = 8.0f;   // log2 units: P bounded by 2^8

    // prologue: stage tile 0 (256 thr x 16B x 8 = 32KB)
    #pragma unroll
    for (int p = 0; p < 8; ++p) {
        const int off = p * 4096 + tid * 16;
        gload_lds16(KVb + off, &sKV[0][off]);
    }

    // P-store addressing (row = q = wv*16 + n16, fixed per lane):
    const int prow  = wv * 16 + n16;
    const int pbase = (prow >> 1) * 128;
    const int pswz  = ((prow >> 1) & 7) << 4;
    const int phalf = (prow & 1) * 64;

    for (int t = 0; t < NT2; ++t) {
        const int buf = t & 1;
        if (t + 1 < NT2) {
            const uint8_t* src = KVb + ((size_t)(t + 1) << 15);
            #pragma unroll
            for (int p = 0; p < 8; ++p) {
                const int off = p * 4096 + tid * 16;
                gload_lds16(src + off, &sKV[buf ^ 1][off]);
            }
            asm volatile("s_waitcnt vmcnt(8)" ::: "memory");  // cur tile done, next in flight
        } else {
            asm volatile("s_waitcnt vmcnt(0)" ::: "memory");
        }
        __builtin_amdgcn_s_barrier();
        asm volatile("" ::: "memory");

        const uint8_t* kb = sKV[buf];

        // ---- S^T = K*Q^T : D[kj][q]; lane holds kj = nc*16+g*4+r, q = n16 ----
        f32x4 st0 = f32x4{0.f, 0.f, 0.f, 0.f};
        f32x4 st1 = f32x4{0.f, 0.f, 0.f, 0.f};
        __builtin_amdgcn_s_setprio(1);
        #pragma unroll
        for (int ks = 0; ks < 8; ++ks) {
            const int r0 = n16;          // kj rows 0-15
            const int r1 = 16 + n16;     // kj rows 16-31
            const bf16x8 kf0 = *(const bf16x8*)(kb + r0 * 512
                                + ((ks * 64 + g * 16) ^ ((r0 & 7) << 4)));
            const bf16x8 kf1 = *(const bf16x8*)(kb + r1 * 512
                                + ((ks * 64 + g * 16) ^ ((r1 & 7) << 4)));
            st0 = __builtin_amdgcn_mfma_f32_16x16x32_bf16(kf0, qf[ks], st0, 0, 0, 0);
            st1 = __builtin_amdgcn_mfma_f32_16x16x32_bf16(kf1, qf[ks], st1, 0, 0, 0);
        }
        __builtin_amdgcn_s_setprio(0);

        // ---- softmax for q = n16: 7 in-reg fmax + 2 shfl over g-groups ----
        float mx = fmaxf(fmaxf(fmaxf(st0[0], st0[1]), fmaxf(st0[2], st0[3])),
                         fmaxf(fmaxf(st1[0], st1[1]), fmaxf(st1[2], st1[3])));
        mx = fmaxf(mx, __shfl_xor(mx, 16));
        mx = fmaxf(mx, __shfl_xor(mx, 32));
        if (!__all(mx - m_i <= DEFER_TH)) {
            const float mnew = fmaxf(m_i, mx);
            const float scl  = exp2f(m_i - mnew);
            m_i = mnew;
            float sclr[4];
            #pragma unroll
            for (int r = 0; r < 4; ++r)
                sclr[r] = __shfl(scl, g * 4 + r);   // scl for acc rows q' = g*4+r
            #pragma unroll
            for (int ds = 0; ds < 16; ++ds)
                #pragma unroll
                for (int r = 0; r < 4; ++r)
                    accO[ds][r] *= sclr[r];
            #pragma unroll
            for (int r = 0; r < 4; ++r)
                accL[r] *= sclr[r];
        }

        // ---- P = exp2(S'-m); packed bf16x4 stores (2 ds_writes/lane) ----
        {
            bf16x4 pk0, pk1;
            #pragma unroll
            for (int r = 0; r < 4; ++r) {
                pk0[r] = (__bf16)exp2f(st0[r] - m_i);
                pk1[r] = (__bf16)exp2f(st1[r] - m_i);
            }
            const int c0b = 2 * (g * 4);          // kj cols g*4..g*4+3 (8B run)
            *(bf16x4*)(sP + pbase + ((phalf + c0b) ^ pswz))      = pk0;
            *(bf16x4*)(sP + pbase + ((phalf + c0b + 32) ^ pswz)) = pk1;  // +16 kj
        }

        // ---- PV: A = P row (n16), B = V pair-swizzled img; +ones-MFMA for l ----
        bf16x8 af;
        {
            const int row = wv * 16 + n16;
            af = *(const bf16x8*)(sP + (row >> 1) * 128
                   + ((((row & 1) * 64) + g * 16) ^ (((row >> 1) & 7) << 4)));
        }
        __builtin_amdgcn_s_setprio(1);
        #pragma unroll
        for (int ds = 0; ds < 16; ++ds) {
            const int d = ds * 16 + n16;
            const bf16x8 vf = *(const bf16x8*)(kb + 16384 + (d >> 1) * 128
                               + ((((d & 1) * 64) + g * 16) ^ (((d >> 1) & 7) << 4)));
            accO[ds] = __builtin_amdgcn_mfma_f32_16x16x32_bf16(af, vf, accO[ds], 0, 0, 0);
        }
        accL = __builtin_amdgcn_mfma_f32_16x16x32_bf16(af, onesf, accL, 0, 0, 0);
        __builtin_amdgcn_s_setprio(0);

        asm volatile("" ::: "memory");
        __builtin_amdgcn_s_barrier();   // all waves done reading buf before overwrite
    }

    // ---- epilogue: O[l][d] = accO / accL (rows already aligned) ----
    float inv[4];
    #pragma unroll
    for (int r = 0; r < 4; ++r) inv[r] = 1.f / accL[r];
    __bf16* Ob = O + ((size_t)b * LSEQ + q0 + wv * 16) * DIN;
    #pragma unroll
    for (int ds = 0; ds < 16; ++ds)
        #pragma unroll
        for (int r = 0; r < 4; ++r)
            Ob[(size_t)(g * 4 + r) * DIN + ds * 16 + n16] = (__bf16)(accO[ds][r] * inv[r]);
}

// ---------------------------------------------------------------------------
// Kernel 3: output projection. out[b][c][l] = sum_i Wo[c][i]*O[b][l][i] + bo[c].
// ---------------------------------------------------------------------------
__global__ __launch_bounds__(256) void out_proj_kernel(
    const float* __restrict__ Wo, const float* __restrict__ bo,
    const __bf16* __restrict__ O, float* __restrict__ out)
{
    const int b   = blockIdx.z;
    const int c0  = blockIdx.y * 64;
    const int l0  = blockIdx.x * 256;
    const int tid = threadIdx.x;
    const int wv  = tid >> 6, lane = tid & 63, g = lane >> 4, n16 = lane & 15;

    __shared__ __align__(16) __bf16 sWo[64][40];   // [c][i]
    __shared__ __align__(16) __bf16 sO[256][40];   // [l][i]

    const __bf16* Ob = O + (size_t)b * LSEQ * DIN;

    f32x4 acc[4][4];
    #pragma unroll
    for (int i = 0; i < 4; ++i)
        #pragma unroll
        for (int j = 0; j < 4; ++j)
            acc[i][j] = f32x4{0.f, 0.f, 0.f, 0.f};

    for (int kk = 0; kk < 8; ++kk) {
        const int i0 = kk * 32;
        __syncthreads();
        #pragma unroll
        for (int p = 0; p < 2; ++p) {
            const int c  = p * 32 + (tid >> 3);
            const int i4 = (tid & 7) * 4;
            const float4 v = *(const float4*)(Wo + (size_t)(c0 + c) * DIN + i0 + i4);
            bf16x4 pk = { (__bf16)v.x, (__bf16)v.y, (__bf16)v.z, (__bf16)v.w };
            *(bf16x4*)&sWo[c][i4] = pk;
        }
        #pragma unroll
        for (int p = 0; p < 4; ++p) {
            const int l  = p * 64 + (tid >> 2);
            const int sg = tid & 3;
            *(uint4*)&sO[l][sg * 8] = *(const uint4*)(Ob + (size_t)(l0 + l) * DIN + i0 + sg * 8);
        }
        __syncthreads();

        bf16x8 af[4], bfr[4];
        #pragma unroll
        for (int mr = 0; mr < 4; ++mr)
            af[mr] = *(const bf16x8*)&sWo[mr * 16 + n16][g * 8];
        #pragma unroll
        for (int nc = 0; nc < 4; ++nc)
            bfr[nc] = *(const bf16x8*)&sO[wv * 64 + nc * 16 + n16][g * 8];
        #pragma unroll
        for (int mr = 0; mr < 4; ++mr)
            #pragma unroll
            for (int nc = 0; nc < 4; ++nc)
                acc[mr][nc] = __builtin_amdgcn_mfma_f32_16x16x32_bf16(
                    af[mr], bfr[nc], acc[mr][nc], 0, 0, 0);
    }

    #pragma unroll
    for (int mr = 0; mr < 4; ++mr) {
        const int c = c0 + mr * 16 + g * 4;
        #pragma unroll
        for (int nc = 0; nc < 4; ++nc) {
            const int l = l0 + wv * 64 + nc * 16 + n16;
            #pragma unroll
            for (int r = 0; r < 4; ++r)
                out[((size_t)b * CH + c + r) * LSEQ + l] = acc[mr][nc][r] + bo[c + r];
        }
    }
}

// ---------------------------------------------------------------------------
extern "C" void kernel_launch(void* const* d_in, const int* in_sizes, int n_in,
                              void* d_out, int out_size, void* d_ws, size_t ws_size,
                              hipStream_t stream)
{
    const float* x  = (const float*)d_in[0];
    const float* Wq = (const float*)d_in[1];
    const float* bq = (const float*)d_in[2];
    const float* Wk = (const float*)d_in[3];
    const float* bk = (const float*)d_in[4];
    const float* Wv = (const float*)d_in[5];
    const float* bv = (const float*)d_in[6];
    const float* Wo = (const float*)d_in[7];
    const float* bo = (const float*)d_in[8];
    float* out = (float*)d_out;

    // ws: Q bf16 16MB | KV swizzled tile images 32MB | O bf16 16MB = 64MB
    __bf16*  Q  = (__bf16*)d_ws;
    uint8_t* KV = (uint8_t*)d_ws + (16u << 20);
    __bf16*  O  = (__bf16*)((uint8_t*)d_ws + (48u << 20));

    qkv_proj_kernel<<<dim3(LSEQ / 64, 3, BS), 256, 0, stream>>>(
        x, Wq, bq, Wk, bk, Wv, bv, Q, KV);
    attn_kernel<<<dim3(BS, LSEQ / 64), 256, 0, stream>>>(Q, KV, O);
    out_proj_kernel<<<dim3(LSEQ / 256, CH / 64, BS), 256, 0, stream>>>(Wo, bo, O, out);
}